// Round 5
// baseline (152.657 us; speedup 1.0000x reference)
//
#include <hip/hip_runtime.h>
#include <hip/hip_bf16.h>

// GAT forward on MI355X. N=4096, IN_F=512, OUT_F=64, HEADS=4, alpha=0.2.
//
// R4 post-mortem: attn became L2-BW-bound re-reading VtF (2 MB x 256 blocks
// = 512 MB / 34.5 TB/s ~ 15us floor). R5: P@V in fp8 e4m3 (halves V bytes;
// p <= ~134 < 448 e4m3 max; fp8 noise washes out over ~2048 neighbors),
// xcast fused into gemm. Pipeline (5 dispatches):
//   wpack  : W -> bf16 MFMA-B-fragment order
//   adjpack: adj -> bitmask (ballot), transposed groups (67 MB -> 2 MB)
//   gemm   : h = x@W (x converted fp32->bf16 in-register); epilogue stores
//            h fragments DUAL: bf16 VtF (for prep) + fp8 VtF8 (for attn)
//   prep   : c_i = e^{-0.8 s_i}, (e^t, e^{0.2t}) per node/head
//   attn   : p = adjbit ? max(et_j, c_i*eat_j) : 0; A-frag packed to fp8
//            in-register; B-frag = dense 512B fp8 loads; rowsum via 5th MFMA
//            with B = fp8(1.0) = 0x38 bytes.

#define NN 4096
#define KF 512
#define NF 256

typedef __attribute__((ext_vector_type(8))) short bf16x8;
typedef __attribute__((ext_vector_type(4))) short s16x4;
typedef __attribute__((ext_vector_type(4))) float f32x4;

union AB8 { bf16x8 v; short2 h[4]; short s[8]; int4 i4; };
union ST4 { s16x4 v; short2 h[2]; };
union I64 { long v; int i[2]; };

__device__ __forceinline__ short f2bf(float f) {
    union { float f; unsigned u; } v; v.f = f;
    unsigned r = v.u + 0x7fffu + ((v.u >> 16) & 1u);  // RNE (finite only)
    return (short)(r >> 16);
}
__device__ __forceinline__ float bf2f(short b) {
    union { unsigned u; float f; } v;
    v.u = ((unsigned)(unsigned short)b) << 16;
    return v.f;
}
__device__ __forceinline__ short2 pkbf(float a, float b) {
    __hip_bfloat162 t = __float22bfloat162_rn(make_float2(a, b));
    union { __hip_bfloat162 v; short2 s; } u; u.v = t;
    return u.s;
}
// pack 4 floats -> 4 fp8 e4m3 bytes (v_cvt_pk_fp8_f32 x2)
__device__ __forceinline__ int pkfp8x4(float a, float b, float c, float d) {
    int p = __builtin_amdgcn_cvt_pk_fp8_f32(a, b, 0, false);
    p     = __builtin_amdgcn_cvt_pk_fp8_f32(c, d, p, true);
    return p;
}

// ---------------- wpack: W -> B-fragment order bf16 ----------------
__global__ __launch_bounds__(256) void wpack(const float* __restrict__ W,
                                             short* __restrict__ WtF) {
    int tid = blockIdx.x * 256 + threadIdx.x;   // 16384 threads
    int l = tid & 63, nt = (tid >> 6) & 3, hd = (tid >> 8) & 3, kblk = tid >> 10;
    int q = l >> 4, r = l & 15;
    int col = hd * 64 + nt * 16 + r;
    int k0 = kblk * 32 + q * 8;
    AB8 o;
    #pragma unroll
    for (int e = 0; e < 8; e++) o.s[e] = f2bf(W[(k0 + e) * NF + col]);
    *(bf16x8*)(WtF + (size_t)tid * 8) = o.v;
}

// ---------------- adjpack: adj -> transposed bit groups ----------------
// uint4 at pT4[w4 * NN + i] = words {w4*4..w4*4+3} of row i (bit j&31 of word j>>5)
__global__ __launch_bounds__(256) void adjpack(const int* __restrict__ adj,
                                               unsigned* __restrict__ pT) {
    int gw   = (blockIdx.x * 256 + threadIdx.x) >> 6;
    int lane = threadIdx.x & 63;
    int i = gw >> 4, seg = gw & 15;
    const int* ap = adj + (size_t)i * NN + seg * 256 + lane;
    unsigned long long b0 = __ballot(ap[0]   != 0);
    unsigned long long b1 = __ballot(ap[64]  != 0);
    unsigned long long b2 = __ballot(ap[128] != 0);
    unsigned long long b3 = __ballot(ap[192] != 0);
    if (lane == 0) {
        *(uint4*)(pT + ((size_t)(seg * 2    ) * NN + i) * 4) =
            make_uint4((unsigned)b0, (unsigned)(b0 >> 32), (unsigned)b1, (unsigned)(b1 >> 32));
        *(uint4*)(pT + ((size_t)(seg * 2 + 1) * NN + i) * 4) =
            make_uint4((unsigned)b2, (unsigned)(b2 >> 32), (unsigned)b3, (unsigned)(b3 >> 32));
    }
}

// ---------------- gemm: h = x@W -> VtF (bf16 frag) + VtF8 (fp8 frag) ----------------
// grid (64,8): bx: 64 j-rows (4 waves x 16); by: hd = by>>1, nt-pair = (by&1)*2.
__global__ __launch_bounds__(256) void gemm(const float* __restrict__ x,
                                            const short* __restrict__ WtF,
                                            short* __restrict__ VtF,
                                            unsigned char* __restrict__ VtF8) {
    const int lane = threadIdx.x & 63, wv = threadIdx.x >> 6;
    const int q = lane >> 4, r = lane & 15;
    const int i0 = blockIdx.x * 64 + wv * 16;
    const int hd = blockIdx.y >> 1, ntp = (blockIdx.y & 1) * 2;

    const float* xp = x + (size_t)(i0 + r) * KF + q * 8;
    const short* wp = WtF + ((size_t)((hd * 4 + ntp) * 64 + lane)) * 8;

    f32x4 acc0 = {}, acc1 = {};
    #pragma unroll 4
    for (int kb = 0; kb < 16; kb++) {
        float4 xa = *(const float4*)(xp + kb * 32);
        float4 xb2 = *(const float4*)(xp + kb * 32 + 4);
        AB8 av;
        av.h[0] = pkbf(xa.x, xa.y);  av.h[1] = pkbf(xa.z, xa.w);
        av.h[2] = pkbf(xb2.x, xb2.y); av.h[3] = pkbf(xb2.z, xb2.w);
        bf16x8 b0 = *(const bf16x8*)(wp + kb * 8192);
        bf16x8 b1 = *(const bf16x8*)(wp + kb * 8192 + 512);
        acc0 = __builtin_amdgcn_mfma_f32_16x16x32_bf16(av.v, b0, acc0, 0, 0, 0);
        acc1 = __builtin_amdgcn_mfma_f32_16x16x32_bf16(av.v, b1, acc1, 0, 0, 0);
    }
    // lane holds h[j=i0+q*4+reg][n]; fragment slot: j-in-32 = (i0&16)+q*4+reg
    const int jblk = i0 >> 5;
    const int base = (i0 & 16) + q * 4;
    const int qa = base >> 3, e0 = base & 7;
    ST4 s0, s1;
    s0.h[0] = pkbf(acc0[0], acc0[1]); s0.h[1] = pkbf(acc0[2], acc0[3]);
    s1.h[0] = pkbf(acc1[0], acc1[1]); s1.h[1] = pkbf(acc1[2], acc1[3]);
    const size_t slot0 = (size_t)(((jblk * 4 + hd) * 4 + ntp    ) * 64 + qa * 16 + r);
    const size_t slot1 = (size_t)(((jblk * 4 + hd) * 4 + ntp + 1) * 64 + qa * 16 + r);
    *(s16x4*)(VtF + slot0 * 8 + e0) = s0.v;
    *(s16x4*)(VtF + slot1 * 8 + e0) = s1.v;
    *(int*)(VtF8 + slot0 * 8 + e0) = pkfp8x4(acc0[0], acc0[1], acc0[2], acc0[3]);
    *(int*)(VtF8 + slot1 * 8 + e0) = pkfp8x4(acc1[0], acc1[1], acc1[2], acc1[3]);
}

// ---------------- prep: c_i = e^{-0.8 s_i}; (e^t, e^{0.2t}) ----------------
// grid 128 (jblk), block 256: wave = head. lane l holds h[j=(l>>4)*8+e][f=nt*16+(l&15)].
__global__ __launch_bounds__(256) void prep(const short* __restrict__ VtF,
                                            const float* __restrict__ a,
                                            float* __restrict__ ipk,
                                            float2* __restrict__ jpk) {
    const int l = threadIdx.x & 63, hd = threadIdx.x >> 6;
    const int q = l >> 4, r = l & 15;
    const int jblk = blockIdx.x;
    float as[4], at[4];
    #pragma unroll
    for (int nt = 0; nt < 4; nt++) { as[nt] = a[nt * 16 + r]; at[nt] = a[64 + nt * 16 + r]; }
    float ps[8] = {}, pt[8] = {};
    #pragma unroll
    for (int nt = 0; nt < 4; nt++) {
        AB8 hv; hv.v = *(const bf16x8*)(VtF + ((size_t)(((jblk * 4 + hd) * 4 + nt) * 64 + l)) * 8);
        #pragma unroll
        for (int e = 0; e < 8; e++) { float v = bf2f(hv.s[e]); ps[e] += v * as[nt]; pt[e] += v * at[nt]; }
    }
    #pragma unroll
    for (int d = 1; d < 16; d <<= 1) {
        #pragma unroll
        for (int e = 0; e < 8; e++) { ps[e] += __shfl_xor(ps[e], d, 64); pt[e] += __shfl_xor(pt[e], d, 64); }
    }
    if (r == 0) {
        #pragma unroll
        for (int e = 0; e < 8; e++) {
            int j = jblk * 32 + q * 8 + e;
            ipk[hd * NN + j] = __expf(-0.8f * ps[e]);
            jpk[hd * NN + j] = make_float2(__expf(pt[e]), __expf(0.2f * pt[e]));
        }
    }
}

// ---------------- attn: fused masked softmax + attn@h (fp8 P@V) ----------------
// grid 256 (16 i-rows), block 1024 = 16 waves: wave = (jq<<2)|hd.
struct PF { float4 ja, jb, jc, jd; long v0, v1, v2, v3; };

__global__ __launch_bounds__(1024) __attribute__((amdgpu_waves_per_eu(1, 4)))
void gat_attn(const uint4* __restrict__ pT4, const float* __restrict__ ipk,
              const float* __restrict__ jpkf, const unsigned char* __restrict__ VtF8,
              float* __restrict__ out) {
    const int tid = threadIdx.x, lane = tid & 63, wv = tid >> 6;
    const int hd = wv & 3, jq = wv >> 2;
    const int q = lane >> 4, r = lane & 15;
    const int i0 = blockIdx.x * 16, i = i0 + r;
    const float ci = ipk[hd * NN + i];          // e^{-0.8 s_i}
    const int qs = q * 8;
    const float* jpf = jpkf + (size_t)hd * NN * 2;

    f32x4 acc[5] = {};
    const long ones = 0x3838383838383838L;      // fp8 e4m3 1.0 bytes

    auto load_pf = [&](PF& p, int it) {
        const float4* jp = (const float4*)(jpf + 2 * ((jq << 10) + (it << 5) + qs));
        p.ja = jp[0]; p.jb = jp[1]; p.jc = jp[2]; p.jd = jp[3];
        const long* vp = (const long*)(VtF8 + (size_t)(((jq * 32 + it) * 16 + hd * 4) * 512) + lane * 8);
        p.v0 = vp[0]; p.v1 = vp[64]; p.v2 = vp[128]; p.v3 = vp[192];
    };
    auto consume = [&](const PF& p, unsigned w) {
        float p0 = (w & 1u)   ? fmaxf(p.ja.x, ci * p.ja.y) : 0.f;
        float p1 = (w & 2u)   ? fmaxf(p.ja.z, ci * p.ja.w) : 0.f;
        float p2 = (w & 4u)   ? fmaxf(p.jb.x, ci * p.jb.y) : 0.f;
        float p3 = (w & 8u)   ? fmaxf(p.jb.z, ci * p.jb.w) : 0.f;
        float p4 = (w & 16u)  ? fmaxf(p.jc.x, ci * p.jc.y) : 0.f;
        float p5 = (w & 32u)  ? fmaxf(p.jc.z, ci * p.jc.w) : 0.f;
        float p6 = (w & 64u)  ? fmaxf(p.jd.x, ci * p.jd.y) : 0.f;
        float p7 = (w & 128u) ? fmaxf(p.jd.z, ci * p.jd.w) : 0.f;
        I64 af;
        af.i[0] = pkfp8x4(p0, p1, p2, p3);
        af.i[1] = pkfp8x4(p4, p5, p6, p7);
        acc[0] = __builtin_amdgcn_mfma_f32_16x16x32_fp8_fp8(af.v, p.v0, acc[0], 0, 0, 0);
        acc[1] = __builtin_amdgcn_mfma_f32_16x16x32_fp8_fp8(af.v, p.v1, acc[1], 0, 0, 0);
        acc[2] = __builtin_amdgcn_mfma_f32_16x16x32_fp8_fp8(af.v, p.v2, acc[2], 0, 0, 0);
        acc[3] = __builtin_amdgcn_mfma_f32_16x16x32_fp8_fp8(af.v, p.v3, acc[3], 0, 0, 0);
        acc[4] = __builtin_amdgcn_mfma_f32_16x16x32_fp8_fp8(af.v, ones, acc[4], 0, 0, 0);
    };

    const uint4* prow = pT4 + (size_t)(jq * 8) * NN + i;   // +NN per word-group
    uint4 wg = prow[0];
    PF pa, pb;
    load_pf(pa, 0);
    #pragma unroll 1
    for (int g = 0; g < 8; g++) {
        uint4 wgn = wg;
        if (g < 7) wgn = prow[(size_t)(g + 1) * NN];
        const int it = g * 4;
        load_pf(pb, it + 1); consume(pa, wg.x >> qs);
        load_pf(pa, it + 2); consume(pb, wg.y >> qs);
        load_pf(pb, it + 3); consume(pa, wg.z >> qs);
        if (g < 7) load_pf(pa, it + 4);
        consume(pb, wg.w >> qs);
        wg = wgn;
    }

    // Combine 4 j-quarters through LDS; rowsum in acc[4] (all cols equal).
    __shared__ float sacc[3][4][5][64][4];
    if (jq > 0) {
        const int gg = jq - 1;
        #pragma unroll
        for (int t = 0; t < 5; t++)
            *(f32x4*)&sacc[gg][hd][t][lane][0] = acc[t];
    }
    __syncthreads();
    if (jq == 0) {
        #pragma unroll
        for (int gg = 0; gg < 3; gg++)
            #pragma unroll
            for (int t = 0; t < 5; t++) {
                f32x4 o = *(const f32x4*)&sacc[gg][hd][t][lane][0];
                acc[t][0] += o[0]; acc[t][1] += o[1];
                acc[t][2] += o[2]; acc[t][3] += o[3];
            }
        #pragma unroll
        for (int reg = 0; reg < 4; reg++) {
            float inv = 1.f / acc[4][reg];
            int row = i0 + q * 4 + reg;
            #pragma unroll
            for (int t = 0; t < 4; t++)
                out[(size_t)row * NF + hd * 64 + t * 16 + r] = acc[t][reg] * inv;
        }
    }
}

extern "C" void kernel_launch(void* const* d_in, const int* in_sizes, int n_in,
                              void* d_out, int out_size, void* d_ws, size_t ws_size,
                              hipStream_t stream) {
    const float* x   = (const float*)d_in[0];
    const int*   adj = (const int*)d_in[1];
    const float* W   = (const float*)d_in[2];
    const float* a   = (const float*)d_in[3];
    float* out = (float*)d_out;

    char* ws = (char*)d_ws;
    short*         WtF  = (short*)ws;                      // 256 KiB
    short*         VtF  = (short*)(ws + 262144);           // 2 MiB
    unsigned char* VtF8 = (unsigned char*)(ws + 2359296);  // 1 MiB
    unsigned*      pT   = (unsigned*)(ws + 3407872);       // 2 MiB
    float*         ipk  = (float*)(ws + 5505024);          // 64 KiB
    float2*        jpk  = (float2*)(ws + 5570560);         // 128 KiB

    wpack  <<<64, 256, 0, stream>>>(W, WtF);
    adjpack<<<16384, 256, 0, stream>>>(adj, pT);
    gemm   <<<dim3(64, 8), 256, 0, stream>>>(x, WtF, VtF, VtF8);
    prep   <<<128, 256, 0, stream>>>(VtF, a, ipk, jpk);
    gat_attn<<<256, 1024, 0, stream>>>((const uint4*)pT, ipk, (const float*)jpk, VtF8, out);
}

// Round 6
// 150.078 us; speedup vs baseline: 1.0172x; 1.0172x over previous
//
#include <hip/hip_runtime.h>
#include <hip/hip_bf16.h>

// GAT forward on MI355X. N=4096, IN_F=512, OUT_F=64, HEADS=4, alpha=0.2.
//
// R5 post-mortem: fp8 V halving was NEUTRAL -> attn not V-BW-bound. Prime
// suspect now gemm: strided fp32 x loads (~32 lines/inst) re-read x8, plus
// prep re-reading VtF. R6 (attn FROZEN for attribution):
//   xpack   : x -> bf16 in MFMA A-fragment order (coalesced both sides)
//   wpack   : W -> bf16 B-fragment order
//   adjpack : adj -> bitmask (ballot), transposed groups (67 MB -> 2 MB)
//   gemmfuse: h = x@W, all-fragment loads (1KB contiguous insts); epilogue
//             stores fp8 V-fragments AND computes s,t from fp32 acc ->
//             ipk = e^{-0.8s}, jpk = (e^t, e^{0.2t}).  (prep kernel + bf16
//             VtF buffer eliminated)
//   attn    : unchanged from R5 (fp8 P@V, bitmask, rowsum via 5th MFMA)

#define NN 4096
#define KF 512
#define NF 256

typedef __attribute__((ext_vector_type(8))) short bf16x8;
typedef __attribute__((ext_vector_type(4))) short s16x4;
typedef __attribute__((ext_vector_type(4))) float f32x4;

union AB8 { bf16x8 v; short2 h[4]; short s[8]; int4 i4; };
union ST4 { s16x4 v; short2 h[2]; };
union I64 { long v; int i[2]; };

__device__ __forceinline__ short f2bf(float f) {
    union { float f; unsigned u; } v; v.f = f;
    unsigned r = v.u + 0x7fffu + ((v.u >> 16) & 1u);  // RNE (finite only)
    return (short)(r >> 16);
}
__device__ __forceinline__ short2 pkbf(float a, float b) {
    __hip_bfloat162 t = __float22bfloat162_rn(make_float2(a, b));
    union { __hip_bfloat162 v; short2 s; } u; u.v = t;
    return u.s;
}
__device__ __forceinline__ int pkfp8x4(float a, float b, float c, float d) {
    int p = __builtin_amdgcn_cvt_pk_fp8_f32(a, b, 0, false);
    p     = __builtin_amdgcn_cvt_pk_fp8_f32(c, d, p, true);
    return p;
}

// ---------------- xpack: x fp32 -> bf16 A-fragment order ----------------
// xF[kblk 16][jgrp 256][lane 64][e 8], lane=(qk<<4)|r: x[jgrp*16+r][kblk*32+qk*8+e]
// Wave: i = bid*4 + wv (const per wave), lane covers k = lane*8..+7 (2KB coalesced read).
__global__ __launch_bounds__(256) void xpack(const float* __restrict__ x,
                                             short* __restrict__ xF) {
    const int lane = threadIdx.x & 63, wv = threadIdx.x >> 6;
    const int i = blockIdx.x * 4 + wv;
    const float4* xp = (const float4*)(x + (size_t)i * KF + lane * 8);
    float4 xa = xp[0], xb = xp[1];
    ST4 o0, o1;
    o0.h[0] = pkbf(xa.x, xa.y); o0.h[1] = pkbf(xa.z, xa.w);
    o1.h[0] = pkbf(xb.x, xb.y); o1.h[1] = pkbf(xb.z, xb.w);
    const int kblk = lane >> 2, qk = lane & 3;
    const int jgrp = i >> 4, r = i & 15;
    short* dst = xF + ((size_t)(kblk * 256 + jgrp) * 64 + qk * 16 + r) * 8;
    *(s16x4*)dst = o0.v;
    *(s16x4*)(dst + 4) = o1.v;
}

// ---------------- wpack: W -> B-fragment order bf16 ----------------
// WtF[kblk 16][hd 4][nt 4][lane 64][e 8]
__global__ __launch_bounds__(256) void wpack(const float* __restrict__ W,
                                             short* __restrict__ WtF) {
    int tid = blockIdx.x * 256 + threadIdx.x;   // 16384 threads
    int l = tid & 63, nt = (tid >> 6) & 3, hd = (tid >> 8) & 3, kblk = tid >> 10;
    int q = l >> 4, r = l & 15;
    int col = hd * 64 + nt * 16 + r;
    int k0 = kblk * 32 + q * 8;
    AB8 o;
    #pragma unroll
    for (int e = 0; e < 8; e++) o.s[e] = f2bf(W[(k0 + e) * NF + col]);
    *(bf16x8*)(WtF + (size_t)tid * 8) = o.v;
}

// ---------------- adjpack: adj -> transposed bit groups ----------------
__global__ __launch_bounds__(256) void adjpack(const int* __restrict__ adj,
                                               unsigned* __restrict__ pT) {
    int gw   = (blockIdx.x * 256 + threadIdx.x) >> 6;
    int lane = threadIdx.x & 63;
    int i = gw >> 4, seg = gw & 15;
    const int* ap = adj + (size_t)i * NN + seg * 256 + lane;
    unsigned long long b0 = __ballot(ap[0]   != 0);
    unsigned long long b1 = __ballot(ap[64]  != 0);
    unsigned long long b2 = __ballot(ap[128] != 0);
    unsigned long long b3 = __ballot(ap[192] != 0);
    if (lane == 0) {
        *(uint4*)(pT + ((size_t)(seg * 2    ) * NN + i) * 4) =
            make_uint4((unsigned)b0, (unsigned)(b0 >> 32), (unsigned)b1, (unsigned)(b1 >> 32));
        *(uint4*)(pT + ((size_t)(seg * 2 + 1) * NN + i) * 4) =
            make_uint4((unsigned)b2, (unsigned)(b2 >> 32), (unsigned)b3, (unsigned)(b3 >> 32));
    }
}

// ---------------- gemmfuse: h = x@W -> VtF8 + ipk/jpk ----------------
// grid 256: jb32 = bid>>1 (32 rows), ch = bid&1 (heads 2ch, 2ch+1).
// 4 waves: rg = wv>>1 (16-row group), head = ch*2 + (wv&1).
__global__ __launch_bounds__(256) void gemmfuse(const short* __restrict__ xF,
                                                const short* __restrict__ WtF,
                                                const float* __restrict__ a,
                                                unsigned char* __restrict__ VtF8,
                                                float* __restrict__ ipk,
                                                float2* __restrict__ jpk) {
    const int lane = threadIdx.x & 63, wv = threadIdx.x >> 6;
    const int q = lane >> 4, r = lane & 15;
    const int jb32 = blockIdx.x >> 1, ch = blockIdx.x & 1;
    const int rg = wv >> 1, hd = ch * 2 + (wv & 1);
    const int jgrp = jb32 * 2 + rg;

    const short* ap = xF  + ((size_t)jgrp * 64 + lane) * 8;            // +kblk*256*512
    const short* wp = WtF + ((size_t)(hd * 4) * 64 + lane) * 8;        // +kblk*16*512, +nt*512

    f32x4 acc[4] = {};
    #pragma unroll
    for (int kblk = 0; kblk < 16; kblk++) {
        bf16x8 av = *(const bf16x8*)(ap + (size_t)kblk * 256 * 512);
        const short* w = wp + (size_t)kblk * 16 * 512;
        #pragma unroll
        for (int nt = 0; nt < 4; nt++) {
            bf16x8 bv = *(const bf16x8*)(w + nt * 512);
            acc[nt] = __builtin_amdgcn_mfma_f32_16x16x32_bf16(av, bv, acc[nt], 0, 0, 0);
        }
    }

    // fp8 V-fragment store: lane holds h[j = jb32*32 + rg*16 + q*4 + reg][n = hd*64+nt*16+r]
    const int base = rg * 16 + q * 4;
    const int qa = base >> 3, e0 = base & 7;
    #pragma unroll
    for (int nt = 0; nt < 4; nt++) {
        size_t slot = (size_t)(((jb32 * 4 + hd) * 4 + nt) * 64 + qa * 16 + r);
        *(int*)(VtF8 + slot * 8 + e0) = pkfp8x4(acc[nt][0], acc[nt][1], acc[nt][2], acc[nt][3]);
    }

    // fused prep: s,t from fp32 acc.  s[row] = sum_{nt,r} acc[nt][reg]*a[nt*16+r]
    float as[4], at[4];
    #pragma unroll
    for (int nt = 0; nt < 4; nt++) { as[nt] = a[nt * 16 + r]; at[nt] = a[64 + nt * 16 + r]; }
    f32x4 sp = {}, tp = {};
    #pragma unroll
    for (int nt = 0; nt < 4; nt++)
        #pragma unroll
        for (int reg = 0; reg < 4; reg++) {
            sp[reg] += acc[nt][reg] * as[nt];
            tp[reg] += acc[nt][reg] * at[nt];
        }
    #pragma unroll
    for (int d = 1; d < 16; d <<= 1)
        #pragma unroll
        for (int reg = 0; reg < 4; reg++) {
            sp[reg] += __shfl_xor(sp[reg], d, 64);
            tp[reg] += __shfl_xor(tp[reg], d, 64);
        }
    if (r == 0) {
        #pragma unroll
        for (int reg = 0; reg < 4; reg++) {
            int j = jb32 * 32 + rg * 16 + q * 4 + reg;
            ipk[hd * NN + j] = __expf(-0.8f * sp[reg]);
            jpk[hd * NN + j] = make_float2(__expf(tp[reg]), __expf(0.2f * tp[reg]));
        }
    }
}

// ---------------- attn: fused masked softmax + attn@h (fp8 P@V) -- UNCHANGED R5 ----------------
struct PF { float4 ja, jb, jc, jd; long v0, v1, v2, v3; };

__global__ __launch_bounds__(1024) __attribute__((amdgpu_waves_per_eu(1, 4)))
void gat_attn(const uint4* __restrict__ pT4, const float* __restrict__ ipk,
              const float* __restrict__ jpkf, const unsigned char* __restrict__ VtF8,
              float* __restrict__ out) {
    const int tid = threadIdx.x, lane = tid & 63, wv = tid >> 6;
    const int hd = wv & 3, jq = wv >> 2;
    const int q = lane >> 4, r = lane & 15;
    const int i0 = blockIdx.x * 16, i = i0 + r;
    const float ci = ipk[hd * NN + i];          // e^{-0.8 s_i}
    const int qs = q * 8;
    const float* jpf = jpkf + (size_t)hd * NN * 2;

    f32x4 acc[5] = {};
    const long ones = 0x3838383838383838L;      // fp8 e4m3 1.0 bytes

    auto load_pf = [&](PF& p, int it) {
        const float4* jp = (const float4*)(jpf + 2 * ((jq << 10) + (it << 5) + qs));
        p.ja = jp[0]; p.jb = jp[1]; p.jc = jp[2]; p.jd = jp[3];
        const long* vp = (const long*)(VtF8 + (size_t)(((jq * 32 + it) * 16 + hd * 4) * 512) + lane * 8);
        p.v0 = vp[0]; p.v1 = vp[64]; p.v2 = vp[128]; p.v3 = vp[192];
    };
    auto consume = [&](const PF& p, unsigned w) {
        float p0 = (w & 1u)   ? fmaxf(p.ja.x, ci * p.ja.y) : 0.f;
        float p1 = (w & 2u)   ? fmaxf(p.ja.z, ci * p.ja.w) : 0.f;
        float p2 = (w & 4u)   ? fmaxf(p.jb.x, ci * p.jb.y) : 0.f;
        float p3 = (w & 8u)   ? fmaxf(p.jb.z, ci * p.jb.w) : 0.f;
        float p4 = (w & 16u)  ? fmaxf(p.jc.x, ci * p.jc.y) : 0.f;
        float p5 = (w & 32u)  ? fmaxf(p.jc.z, ci * p.jc.w) : 0.f;
        float p6 = (w & 64u)  ? fmaxf(p.jd.x, ci * p.jd.y) : 0.f;
        float p7 = (w & 128u) ? fmaxf(p.jd.z, ci * p.jd.w) : 0.f;
        I64 af;
        af.i[0] = pkfp8x4(p0, p1, p2, p3);
        af.i[1] = pkfp8x4(p4, p5, p6, p7);
        acc[0] = __builtin_amdgcn_mfma_f32_16x16x32_fp8_fp8(af.v, p.v0, acc[0], 0, 0, 0);
        acc[1] = __builtin_amdgcn_mfma_f32_16x16x32_fp8_fp8(af.v, p.v1, acc[1], 0, 0, 0);
        acc[2] = __builtin_amdgcn_mfma_f32_16x16x32_fp8_fp8(af.v, p.v2, acc[2], 0, 0, 0);
        acc[3] = __builtin_amdgcn_mfma_f32_16x16x32_fp8_fp8(af.v, p.v3, acc[3], 0, 0, 0);
        acc[4] = __builtin_amdgcn_mfma_f32_16x16x32_fp8_fp8(af.v, ones, acc[4], 0, 0, 0);
    };

    const uint4* prow = pT4 + (size_t)(jq * 8) * NN + i;
    uint4 wg = prow[0];
    PF pa, pb;
    load_pf(pa, 0);
    #pragma unroll 1
    for (int g = 0; g < 8; g++) {
        uint4 wgn = wg;
        if (g < 7) wgn = prow[(size_t)(g + 1) * NN];
        const int it = g * 4;
        load_pf(pb, it + 1); consume(pa, wg.x >> qs);
        load_pf(pa, it + 2); consume(pb, wg.y >> qs);
        load_pf(pb, it + 3); consume(pa, wg.z >> qs);
        if (g < 7) load_pf(pa, it + 4);
        consume(pb, wg.w >> qs);
        wg = wgn;
    }

    __shared__ float sacc[3][4][5][64][4];
    if (jq > 0) {
        const int gg = jq - 1;
        #pragma unroll
        for (int t = 0; t < 5; t++)
            *(f32x4*)&sacc[gg][hd][t][lane][0] = acc[t];
    }
    __syncthreads();
    if (jq == 0) {
        #pragma unroll
        for (int gg = 0; gg < 3; gg++)
            #pragma unroll
            for (int t = 0; t < 5; t++) {
                f32x4 o = *(const f32x4*)&sacc[gg][hd][t][lane][0];
                acc[t][0] += o[0]; acc[t][1] += o[1];
                acc[t][2] += o[2]; acc[t][3] += o[3];
            }
        #pragma unroll
        for (int reg = 0; reg < 4; reg++) {
            float inv = 1.f / acc[4][reg];
            int row = i0 + q * 4 + reg;
            #pragma unroll
            for (int t = 0; t < 4; t++)
                out[(size_t)row * NF + hd * 64 + t * 16 + r] = acc[t][reg] * inv;
        }
    }
}

extern "C" void kernel_launch(void* const* d_in, const int* in_sizes, int n_in,
                              void* d_out, int out_size, void* d_ws, size_t ws_size,
                              hipStream_t stream) {
    const float* x   = (const float*)d_in[0];
    const int*   adj = (const int*)d_in[1];
    const float* W   = (const float*)d_in[2];
    const float* a   = (const float*)d_in[3];
    float* out = (float*)d_out;

    char* ws = (char*)d_ws;
    short*         xF   = (short*)ws;                      // 4 MiB
    short*         WtF  = (short*)(ws + 4194304);          // 256 KiB
    unsigned char* VtF8 = (unsigned char*)(ws + 4456448);  // 1 MiB
    unsigned*      pT   = (unsigned*)(ws + 5505024);       // 2 MiB
    float*         ipk  = (float*)(ws + 7602176);          // 64 KiB
    float2*        jpk  = (float2*)(ws + 7667712);         // 128 KiB

    xpack   <<<1024, 256, 0, stream>>>(x, xF);
    wpack   <<<64, 256, 0, stream>>>(W, WtF);
    adjpack <<<16384, 256, 0, stream>>>(adj, pT);
    gemmfuse<<<256, 256, 0, stream>>>(xF, WtF, a, VtF8, ipk, jpk);
    gat_attn<<<256, 1024, 0, stream>>>((const uint4*)pT, ipk, (const float*)jpk, VtF8, out);
}

// Round 7
// 141.732 us; speedup vs baseline: 1.0771x; 1.0589x over previous
//
#include <hip/hip_runtime.h>
#include <hip/hip_bf16.h>

// GAT forward on MI355X. N=4096, IN_F=512, OUT_F=64, HEADS=4, alpha=0.2.
//
// R6 post-mortem: gemm overhaul neutral -> attn (~34us, unchanged since R4) is
// the big movable block. Diagnosis: 16-wave blocks with VGPR>64 -> only 1
// block/CU (4 waves/SIMD) -> L2-latency stalls (x4 over issue floor).
// R7: attn re-gridded to 1024 blocks x 512 thr (wave = j-eighth, 16 iters),
// __launch_bounds__(512,8) caps VGPR<=64 -> 4 blocks/CU = 32 waves/CU;
// single-buffered loads (TLP replaces manual pipelining). Dispatch fusion:
//   K1: xpack + wpack     K2: gemmfuse + adjpack (overlap)     K3: attn

#define NN 4096
#define KF 512
#define NF 256

typedef __attribute__((ext_vector_type(8))) short bf16x8;
typedef __attribute__((ext_vector_type(4))) short s16x4;
typedef __attribute__((ext_vector_type(4))) float f32x4;

union AB8 { bf16x8 v; short2 h[4]; short s[8]; int4 i4; };
union ST4 { s16x4 v; short2 h[2]; };
union I64 { long v; int i[2]; };

__device__ __forceinline__ short f2bf(float f) {
    union { float f; unsigned u; } v; v.f = f;
    unsigned r = v.u + 0x7fffu + ((v.u >> 16) & 1u);  // RNE (finite only)
    return (short)(r >> 16);
}
__device__ __forceinline__ short2 pkbf(float a, float b) {
    __hip_bfloat162 t = __float22bfloat162_rn(make_float2(a, b));
    union { __hip_bfloat162 v; short2 s; } u; u.v = t;
    return u.s;
}
__device__ __forceinline__ int pkfp8x4(float a, float b, float c, float d) {
    int p = __builtin_amdgcn_cvt_pk_fp8_f32(a, b, 0, false);
    p     = __builtin_amdgcn_cvt_pk_fp8_f32(c, d, p, true);
    return p;
}

// ---------------- K1: xpack (bid<1024) + wpack (bid>=1024) ----------------
// xF[kblk 16][jgrp 256][lane 64][e 8]; WtF[kblk 16][hd 4][nt 4][lane 64][e 8]
__global__ __launch_bounds__(256) void stage1(const float* __restrict__ x,
                                              const float* __restrict__ W,
                                              short* __restrict__ xF,
                                              short* __restrict__ WtF) {
    if (blockIdx.x < 1024) {
        const int lane = threadIdx.x & 63, wv = threadIdx.x >> 6;
        const int i = blockIdx.x * 4 + wv;
        const float4* xp = (const float4*)(x + (size_t)i * KF + lane * 8);
        float4 xa = xp[0], xb = xp[1];
        ST4 o0, o1;
        o0.h[0] = pkbf(xa.x, xa.y); o0.h[1] = pkbf(xa.z, xa.w);
        o1.h[0] = pkbf(xb.x, xb.y); o1.h[1] = pkbf(xb.z, xb.w);
        const int kblk = lane >> 2, qk = lane & 3;
        const int jgrp = i >> 4, r = i & 15;
        short* dst = xF + ((size_t)(kblk * 256 + jgrp) * 64 + qk * 16 + r) * 8;
        *(s16x4*)dst = o0.v;
        *(s16x4*)(dst + 4) = o1.v;
    } else {
        int tid = (blockIdx.x - 1024) * 256 + threadIdx.x;   // 16384 threads
        int l = tid & 63, nt = (tid >> 6) & 3, hd = (tid >> 8) & 3, kblk = tid >> 10;
        int q = l >> 4, r = l & 15;
        int col = hd * 64 + nt * 16 + r;
        int k0 = kblk * 32 + q * 8;
        AB8 o;
        #pragma unroll
        for (int e = 0; e < 8; e++) o.s[e] = f2bf(W[(k0 + e) * NF + col]);
        *(bf16x8*)(WtF + (size_t)tid * 8) = o.v;
    }
}

// ---------------- K2: gemmfuse (bid<256) + adjpack (bid>=256) ----------------
__global__ __launch_bounds__(256) void stage2(const short* __restrict__ xF,
                                              const short* __restrict__ WtF,
                                              const float* __restrict__ a,
                                              const int* __restrict__ adj,
                                              unsigned char* __restrict__ VtF8,
                                              float* __restrict__ ipk,
                                              float2* __restrict__ jpk,
                                              unsigned* __restrict__ pT) {
    if (blockIdx.x < 256) {
        // ---- gemmfuse: h = x@W -> fp8 V-fragments + ipk/jpk ----
        const int lane = threadIdx.x & 63, wv = threadIdx.x >> 6;
        const int q = lane >> 4, r = lane & 15;
        const int jb32 = blockIdx.x >> 1, ch = blockIdx.x & 1;
        const int rg = wv >> 1, hd = ch * 2 + (wv & 1);
        const int jgrp = jb32 * 2 + rg;

        const short* ap = xF  + ((size_t)jgrp * 64 + lane) * 8;
        const short* wp = WtF + ((size_t)(hd * 4) * 64 + lane) * 8;

        f32x4 acc[4] = {};
        #pragma unroll
        for (int kblk = 0; kblk < 16; kblk++) {
            bf16x8 av = *(const bf16x8*)(ap + (size_t)kblk * 256 * 512);
            const short* w = wp + (size_t)kblk * 16 * 512;
            #pragma unroll
            for (int nt = 0; nt < 4; nt++) {
                bf16x8 bv = *(const bf16x8*)(w + nt * 512);
                acc[nt] = __builtin_amdgcn_mfma_f32_16x16x32_bf16(av, bv, acc[nt], 0, 0, 0);
            }
        }
        const int base = rg * 16 + q * 4;
        const int qa = base >> 3, e0 = base & 7;
        #pragma unroll
        for (int nt = 0; nt < 4; nt++) {
            size_t slot = (size_t)(((jb32 * 4 + hd) * 4 + nt) * 64 + qa * 16 + r);
            *(int*)(VtF8 + slot * 8 + e0) = pkfp8x4(acc[nt][0], acc[nt][1], acc[nt][2], acc[nt][3]);
        }
        float as[4], at[4];
        #pragma unroll
        for (int nt = 0; nt < 4; nt++) { as[nt] = a[nt * 16 + r]; at[nt] = a[64 + nt * 16 + r]; }
        f32x4 sp = {}, tp = {};
        #pragma unroll
        for (int nt = 0; nt < 4; nt++)
            #pragma unroll
            for (int reg = 0; reg < 4; reg++) {
                sp[reg] += acc[nt][reg] * as[nt];
                tp[reg] += acc[nt][reg] * at[nt];
            }
        #pragma unroll
        for (int d = 1; d < 16; d <<= 1)
            #pragma unroll
            for (int reg = 0; reg < 4; reg++) {
                sp[reg] += __shfl_xor(sp[reg], d, 64);
                tp[reg] += __shfl_xor(tp[reg], d, 64);
            }
        if (r == 0) {
            #pragma unroll
            for (int reg = 0; reg < 4; reg++) {
                int j = jb32 * 32 + rg * 16 + q * 4 + reg;
                ipk[hd * NN + j] = __expf(-0.8f * sp[reg]);
                jpk[hd * NN + j] = make_float2(__expf(tp[reg]), __expf(0.2f * tp[reg]));
            }
        }
    } else {
        // ---- adjpack: adj -> transposed bit groups ----
        int gw   = ((blockIdx.x - 256) * 256 + threadIdx.x) >> 6;
        int lane = threadIdx.x & 63;
        int i = gw >> 4, seg = gw & 15;
        const int* ap = adj + (size_t)i * NN + seg * 256 + lane;
        unsigned long long b0 = __ballot(ap[0]   != 0);
        unsigned long long b1 = __ballot(ap[64]  != 0);
        unsigned long long b2 = __ballot(ap[128] != 0);
        unsigned long long b3 = __ballot(ap[192] != 0);
        if (lane == 0) {
            *(uint4*)(pT + ((size_t)(seg * 2    ) * NN + i) * 4) =
                make_uint4((unsigned)b0, (unsigned)(b0 >> 32), (unsigned)b1, (unsigned)(b1 >> 32));
            *(uint4*)(pT + ((size_t)(seg * 2 + 1) * NN + i) * 4) =
                make_uint4((unsigned)b2, (unsigned)(b2 >> 32), (unsigned)b3, (unsigned)(b3 >> 32));
        }
    }
}

// ---------------- K3: attn -- fused masked softmax + attn@h (fp8 P@V) ----------------
// grid 1024 = 256 i-tiles x 4 heads; block 512 = 8 waves = 8 j-eighths (16 iters).
// __launch_bounds__(512,8): VGPR<=64 -> 4 blocks/CU = 32 waves/CU.
__global__ __launch_bounds__(512, 8)
void gat_attn(const uint4* __restrict__ pT4, const float* __restrict__ ipk,
              const float* __restrict__ jpkf, const unsigned char* __restrict__ VtF8,
              float* __restrict__ out) {
    const int lane = threadIdx.x & 63, js = threadIdx.x >> 6;   // j-eighth 0..7
    const int hd = blockIdx.x & 3, itile = blockIdx.x >> 2;
    const int q = lane >> 4, r = lane & 15;
    const int i0 = itile * 16, i = i0 + r;
    const float ci = ipk[hd * NN + i];          // e^{-0.8 s_i}
    const int qs = q * 8;

    f32x4 acc[5] = {};
    const long ones = 0x3838383838383838L;      // fp8 e4m3 1.0 bytes

    const int it0 = js * 16;                    // first 32-j iter of this wave
    const float* jp = jpkf + (size_t)hd * NN * 2 + 2 * ((it0 << 5) + qs);
    const long*  vp = (const long*)(VtF8 + (size_t)(it0 * 16 + hd * 4) * 512) + lane;
    const uint4* prow = pT4 + (size_t)(js * 4) * NN + i;

    auto consume = [&](unsigned w, float4 ja, float4 jb, float4 jc, float4 jd,
                       long v0, long v1, long v2, long v3) {
        float p0 = (w & 1u)   ? fmaxf(ja.x, ci * ja.y) : 0.f;
        float p1 = (w & 2u)   ? fmaxf(ja.z, ci * ja.w) : 0.f;
        float p2 = (w & 4u)   ? fmaxf(jb.x, ci * jb.y) : 0.f;
        float p3 = (w & 8u)   ? fmaxf(jb.z, ci * jb.w) : 0.f;
        float p4 = (w & 16u)  ? fmaxf(jc.x, ci * jc.y) : 0.f;
        float p5 = (w & 32u)  ? fmaxf(jc.z, ci * jc.w) : 0.f;
        float p6 = (w & 64u)  ? fmaxf(jd.x, ci * jd.y) : 0.f;
        float p7 = (w & 128u) ? fmaxf(jd.z, ci * jd.w) : 0.f;
        I64 af;
        af.i[0] = pkfp8x4(p0, p1, p2, p3);
        af.i[1] = pkfp8x4(p4, p5, p6, p7);
        acc[0] = __builtin_amdgcn_mfma_f32_16x16x32_fp8_fp8(af.v, v0, acc[0], 0, 0, 0);
        acc[1] = __builtin_amdgcn_mfma_f32_16x16x32_fp8_fp8(af.v, v1, acc[1], 0, 0, 0);
        acc[2] = __builtin_amdgcn_mfma_f32_16x16x32_fp8_fp8(af.v, v2, acc[2], 0, 0, 0);
        acc[3] = __builtin_amdgcn_mfma_f32_16x16x32_fp8_fp8(af.v, v3, acc[3], 0, 0, 0);
        acc[4] = __builtin_amdgcn_mfma_f32_16x16x32_fp8_fp8(af.v, ones, acc[4], 0, 0, 0);
    };

    #pragma unroll 1
    for (int g = 0; g < 4; g++) {
        uint4 wg = prow[(size_t)g * NN];
        #pragma unroll
        for (int u = 0; u < 4; u++) {
            unsigned w = (u == 0 ? wg.x : u == 1 ? wg.y : u == 2 ? wg.z : wg.w) >> qs;
            const float4* jpv = (const float4*)jp;
            consume(w, jpv[0], jpv[1], jpv[2], jpv[3], vp[0], vp[64], vp[128], vp[192]);
            jp += 64; vp += 1024;
        }
    }

    // Combine 8 j-eighths through LDS; rowsum in acc[4] (all cols equal).
    __shared__ float sacc[7][5][64][4];   // 35840 B
    if (js > 0) {
        #pragma unroll
        for (int t = 0; t < 5; t++)
            *(f32x4*)&sacc[js - 1][t][lane][0] = acc[t];
    }
    __syncthreads();
    if (js == 0) {
        #pragma unroll 1
        for (int gg = 0; gg < 7; gg++)
            #pragma unroll
            for (int t = 0; t < 5; t++) {
                f32x4 o = *(const f32x4*)&sacc[gg][t][lane][0];
                acc[t][0] += o[0]; acc[t][1] += o[1];
                acc[t][2] += o[2]; acc[t][3] += o[3];
            }
        #pragma unroll
        for (int reg = 0; reg < 4; reg++) {
            float inv = 1.f / acc[4][reg];
            int row = i0 + q * 4 + reg;
            #pragma unroll
            for (int t = 0; t < 4; t++)
                out[(size_t)row * NF + hd * 64 + t * 16 + r] = acc[t][reg] * inv;
        }
    }
}

extern "C" void kernel_launch(void* const* d_in, const int* in_sizes, int n_in,
                              void* d_out, int out_size, void* d_ws, size_t ws_size,
                              hipStream_t stream) {
    const float* x   = (const float*)d_in[0];
    const int*   adj = (const int*)d_in[1];
    const float* W   = (const float*)d_in[2];
    const float* a   = (const float*)d_in[3];
    float* out = (float*)d_out;

    char* ws = (char*)d_ws;
    short*         xF   = (short*)ws;                      // 4 MiB
    short*         WtF  = (short*)(ws + 4194304);          // 256 KiB
    unsigned char* VtF8 = (unsigned char*)(ws + 4456448);  // 1 MiB
    unsigned*      pT   = (unsigned*)(ws + 5505024);       // 2 MiB
    float*         ipk  = (float*)(ws + 7602176);          // 64 KiB
    float2*        jpk  = (float2*)(ws + 7667712);         // 128 KiB

    stage1  <<<1088, 256, 0, stream>>>(x, W, xF, WtF);
    stage2  <<<16640, 256, 0, stream>>>(xF, WtF, a, adj, VtF8, ipk, jpk, pT);
    gat_attn<<<1024, 512, 0, stream>>>((const uint4*)pT, ipk, (const float*)jpk, VtF8, out);
}

// Round 8
// 127.904 us; speedup vs baseline: 1.1935x; 1.1081x over previous
//
#include <hip/hip_runtime.h>
#include <hip/hip_bf16.h>

// GAT forward on MI355X. N=4096, IN_F=512, OUT_F=64, HEADS=4, alpha=0.2.
//
// R7 post-mortem: attn still ~28us (~3x floor). R8 attn v3:
//  - each wave handles 2 i-tiles (32 rows) sharing V/jpk loads -> 512 blocks,
//    L2 traffic halves (~150 MB ~ 4.4us floor)
//  - launch_bounds(512,4): VGPR<=128, 2 blocks/CU = 16 waves/CU (room to
//    pipeline loads, unlike R7's 64-VGPR squeeze)
//  - adjacency mask applied as byte-AND on packed fp8 via 16-entry LDS LUT
//    (kills the 8x and+cmp+cndmask chain per i-set)
// K1: xpack+wpack   K2: gemmfuse+adjpack   K3: attn

#define NN 4096
#define KF 512
#define NF 256

typedef __attribute__((ext_vector_type(8))) short bf16x8;
typedef __attribute__((ext_vector_type(4))) short s16x4;
typedef __attribute__((ext_vector_type(4))) float f32x4;

union AB8 { bf16x8 v; short2 h[4]; short s[8]; int4 i4; };
union ST4 { s16x4 v; short2 h[2]; };
union I64 { long v; int i[2]; };

__device__ __forceinline__ short f2bf(float f) {
    union { float f; unsigned u; } v; v.f = f;
    unsigned r = v.u + 0x7fffu + ((v.u >> 16) & 1u);  // RNE (finite only)
    return (short)(r >> 16);
}
__device__ __forceinline__ short2 pkbf(float a, float b) {
    __hip_bfloat162 t = __float22bfloat162_rn(make_float2(a, b));
    union { __hip_bfloat162 v; short2 s; } u; u.v = t;
    return u.s;
}
__device__ __forceinline__ int pkfp8x4(float a, float b, float c, float d) {
    int p = __builtin_amdgcn_cvt_pk_fp8_f32(a, b, 0, false);
    p     = __builtin_amdgcn_cvt_pk_fp8_f32(c, d, p, true);
    return p;
}

// ---------------- K1: xpack (bid<1024) + wpack (bid>=1024) ----------------
__global__ __launch_bounds__(256) void stage1(const float* __restrict__ x,
                                              const float* __restrict__ W,
                                              short* __restrict__ xF,
                                              short* __restrict__ WtF) {
    if (blockIdx.x < 1024) {
        const int lane = threadIdx.x & 63, wv = threadIdx.x >> 6;
        const int i = blockIdx.x * 4 + wv;
        const float4* xp = (const float4*)(x + (size_t)i * KF + lane * 8);
        float4 xa = xp[0], xb = xp[1];
        ST4 o0, o1;
        o0.h[0] = pkbf(xa.x, xa.y); o0.h[1] = pkbf(xa.z, xa.w);
        o1.h[0] = pkbf(xb.x, xb.y); o1.h[1] = pkbf(xb.z, xb.w);
        const int kblk = lane >> 2, qk = lane & 3;
        const int jgrp = i >> 4, r = i & 15;
        short* dst = xF + ((size_t)(kblk * 256 + jgrp) * 64 + qk * 16 + r) * 8;
        *(s16x4*)dst = o0.v;
        *(s16x4*)(dst + 4) = o1.v;
    } else {
        int tid = (blockIdx.x - 1024) * 256 + threadIdx.x;   // 16384 threads
        int l = tid & 63, nt = (tid >> 6) & 3, hd = (tid >> 8) & 3, kblk = tid >> 10;
        int q = l >> 4, r = l & 15;
        int col = hd * 64 + nt * 16 + r;
        int k0 = kblk * 32 + q * 8;
        AB8 o;
        #pragma unroll
        for (int e = 0; e < 8; e++) o.s[e] = f2bf(W[(k0 + e) * NF + col]);
        *(bf16x8*)(WtF + (size_t)tid * 8) = o.v;
    }
}

// ---------------- K2: gemmfuse (bid<256) + adjpack (bid>=256) ----------------
__global__ __launch_bounds__(256) void stage2(const short* __restrict__ xF,
                                              const short* __restrict__ WtF,
                                              const float* __restrict__ a,
                                              const int* __restrict__ adj,
                                              unsigned char* __restrict__ VtF8,
                                              float* __restrict__ ipk,
                                              float2* __restrict__ jpk,
                                              unsigned* __restrict__ pT) {
    if (blockIdx.x < 256) {
        const int lane = threadIdx.x & 63, wv = threadIdx.x >> 6;
        const int q = lane >> 4, r = lane & 15;
        const int jb32 = blockIdx.x >> 1, ch = blockIdx.x & 1;
        const int rg = wv >> 1, hd = ch * 2 + (wv & 1);
        const int jgrp = jb32 * 2 + rg;

        const short* ap = xF  + ((size_t)jgrp * 64 + lane) * 8;
        const short* wp = WtF + ((size_t)(hd * 4) * 64 + lane) * 8;

        f32x4 acc[4] = {};
        #pragma unroll
        for (int kblk = 0; kblk < 16; kblk++) {
            bf16x8 av = *(const bf16x8*)(ap + (size_t)kblk * 256 * 512);
            const short* w = wp + (size_t)kblk * 16 * 512;
            #pragma unroll
            for (int nt = 0; nt < 4; nt++) {
                bf16x8 bv = *(const bf16x8*)(w + nt * 512);
                acc[nt] = __builtin_amdgcn_mfma_f32_16x16x32_bf16(av, bv, acc[nt], 0, 0, 0);
            }
        }
        const int base = rg * 16 + q * 4;
        const int qa = base >> 3, e0 = base & 7;
        #pragma unroll
        for (int nt = 0; nt < 4; nt++) {
            size_t slot = (size_t)(((jb32 * 4 + hd) * 4 + nt) * 64 + qa * 16 + r);
            *(int*)(VtF8 + slot * 8 + e0) = pkfp8x4(acc[nt][0], acc[nt][1], acc[nt][2], acc[nt][3]);
        }
        float as[4], at[4];
        #pragma unroll
        for (int nt = 0; nt < 4; nt++) { as[nt] = a[nt * 16 + r]; at[nt] = a[64 + nt * 16 + r]; }
        f32x4 sp = {}, tp = {};
        #pragma unroll
        for (int nt = 0; nt < 4; nt++)
            #pragma unroll
            for (int reg = 0; reg < 4; reg++) {
                sp[reg] += acc[nt][reg] * as[nt];
                tp[reg] += acc[nt][reg] * at[nt];
            }
        #pragma unroll
        for (int d = 1; d < 16; d <<= 1)
            #pragma unroll
            for (int reg = 0; reg < 4; reg++) {
                sp[reg] += __shfl_xor(sp[reg], d, 64);
                tp[reg] += __shfl_xor(tp[reg], d, 64);
            }
        if (r == 0) {
            #pragma unroll
            for (int reg = 0; reg < 4; reg++) {
                int j = jb32 * 32 + rg * 16 + q * 4 + reg;
                ipk[hd * NN + j] = __expf(-0.8f * sp[reg]);
                jpk[hd * NN + j] = make_float2(__expf(tp[reg]), __expf(0.2f * tp[reg]));
            }
        }
    } else {
        int gw   = ((blockIdx.x - 256) * 256 + threadIdx.x) >> 6;
        int lane = threadIdx.x & 63;
        int i = gw >> 4, seg = gw & 15;
        const int* ap = adj + (size_t)i * NN + seg * 256 + lane;
        unsigned long long b0 = __ballot(ap[0]   != 0);
        unsigned long long b1 = __ballot(ap[64]  != 0);
        unsigned long long b2 = __ballot(ap[128] != 0);
        unsigned long long b3 = __ballot(ap[192] != 0);
        if (lane == 0) {
            *(uint4*)(pT + ((size_t)(seg * 2    ) * NN + i) * 4) =
                make_uint4((unsigned)b0, (unsigned)(b0 >> 32), (unsigned)b1, (unsigned)(b1 >> 32));
            *(uint4*)(pT + ((size_t)(seg * 2 + 1) * NN + i) * 4) =
                make_uint4((unsigned)b2, (unsigned)(b2 >> 32), (unsigned)b3, (unsigned)(b3 >> 32));
        }
    }
}

// ---------------- K3: attn v3 -- 2 i-tiles/wave, LUT mask, fp8 P@V ----------------
// grid 512 = 128 itile32 x 4 heads; block 512 = 8 waves = 8 j-eighths (16 iters).
// launch_bounds(512,4): VGPR<=128, 2 blocks/CU = 16 waves/CU.
__global__ __launch_bounds__(512, 4)
void gat_attn(const uint4* __restrict__ pT4, const float* __restrict__ ipk,
              const float* __restrict__ jpkf, const unsigned char* __restrict__ VtF8,
              float* __restrict__ out) {
    const int lane = threadIdx.x & 63, js = threadIdx.x >> 6;   // j-eighth 0..7
    const int hd = blockIdx.x & 3, it32 = blockIdx.x >> 2;
    const int q = lane >> 4, r = lane & 15;
    const int i0 = it32 * 32, ia = i0 + r;
    const float cia = ipk[hd * NN + ia];
    const float cib = ipk[hd * NN + ia + 16];
    const int qs = q * 8;

    __shared__ unsigned lut[16];
    __shared__ float sacc[7][10][64][4];   // 71680 B
    if (threadIdx.x < 16) {
        unsigned m01 = (threadIdx.x * 0x204081u) & 0x01010101u;
        lut[threadIdx.x] = m01 * 0xFFu;    // byte e = 0xFF iff bit e of idx
    }
    __syncthreads();

    f32x4 acc[10] = {};
    const long ones = 0x3838383838383838L;      // fp8 e4m3 1.0 bytes

    const int it0 = js * 16;
    const float* jp = jpkf + (size_t)hd * NN * 2 + 2 * ((it0 << 5) + qs);
    const long*  vp = (const long*)(VtF8 + (size_t)(it0 * 16 + hd * 4) * 512) + lane;
    const uint4* prow = pT4 + (size_t)(js * 4) * NN + ia;

    auto iset = [&](unsigned w, float ci, f32x4* ac,
                    float4 ja, float4 jb, float4 jc, float4 jd,
                    long v0, long v1, long v2, long v3) {
        float p0 = fmaxf(ja.x, ci * ja.y);
        float p1 = fmaxf(ja.z, ci * ja.w);
        float p2 = fmaxf(jb.x, ci * jb.y);
        float p3 = fmaxf(jb.z, ci * jb.w);
        float p4 = fmaxf(jc.x, ci * jc.y);
        float p5 = fmaxf(jc.z, ci * jc.w);
        float p6 = fmaxf(jd.x, ci * jd.y);
        float p7 = fmaxf(jd.z, ci * jd.w);
        I64 af;
        af.i[0] = pkfp8x4(p0, p1, p2, p3) & (int)lut[w & 15u];
        af.i[1] = pkfp8x4(p4, p5, p6, p7) & (int)lut[(w >> 4) & 15u];
        ac[0] = __builtin_amdgcn_mfma_f32_16x16x32_fp8_fp8(af.v, v0, ac[0], 0, 0, 0);
        ac[1] = __builtin_amdgcn_mfma_f32_16x16x32_fp8_fp8(af.v, v1, ac[1], 0, 0, 0);
        ac[2] = __builtin_amdgcn_mfma_f32_16x16x32_fp8_fp8(af.v, v2, ac[2], 0, 0, 0);
        ac[3] = __builtin_amdgcn_mfma_f32_16x16x32_fp8_fp8(af.v, v3, ac[3], 0, 0, 0);
        ac[4] = __builtin_amdgcn_mfma_f32_16x16x32_fp8_fp8(af.v, ones, ac[4], 0, 0, 0);
    };

    #pragma unroll 1
    for (int g = 0; g < 4; g++) {
        uint4 wga = prow[(size_t)g * NN];
        uint4 wgb = prow[(size_t)g * NN + 16];
        #pragma unroll
        for (int u = 0; u < 4; u++) {
            unsigned wa = (u == 0 ? wga.x : u == 1 ? wga.y : u == 2 ? wga.z : wga.w) >> qs;
            unsigned wb = (u == 0 ? wgb.x : u == 1 ? wgb.y : u == 2 ? wgb.z : wgb.w) >> qs;
            const float4* jpv = (const float4*)jp;
            float4 ja = jpv[0], jb = jpv[1], jc = jpv[2], jd = jpv[3];
            long v0 = vp[0], v1 = vp[64], v2 = vp[128], v3 = vp[192];
            iset(wa, cia, acc,     ja, jb, jc, jd, v0, v1, v2, v3);
            iset(wb, cib, acc + 5, ja, jb, jc, jd, v0, v1, v2, v3);
            jp += 64; vp += 1024;
        }
    }

    // Combine 8 j-eighths through LDS; rowsums in acc[4]/acc[9].
    if (js > 0) {
        #pragma unroll
        for (int t = 0; t < 10; t++)
            *(f32x4*)&sacc[js - 1][t][lane][0] = acc[t];
    }
    __syncthreads();
    if (js == 0) {
        #pragma unroll 1
        for (int gg = 0; gg < 7; gg++)
            #pragma unroll
            for (int t = 0; t < 10; t++) {
                f32x4 o = *(const f32x4*)&sacc[gg][t][lane][0];
                acc[t][0] += o[0]; acc[t][1] += o[1];
                acc[t][2] += o[2]; acc[t][3] += o[3];
            }
        #pragma unroll
        for (int reg = 0; reg < 4; reg++) {
            float inva = 1.f / acc[4][reg];
            float invb = 1.f / acc[9][reg];
            int rowa = i0 + q * 4 + reg;
            #pragma unroll
            for (int t = 0; t < 4; t++) {
                out[(size_t)rowa * NF + hd * 64 + t * 16 + r] = acc[t][reg] * inva;
                out[(size_t)(rowa + 16) * NF + hd * 64 + t * 16 + r] = acc[t + 5][reg] * invb;
            }
        }
    }
}

extern "C" void kernel_launch(void* const* d_in, const int* in_sizes, int n_in,
                              void* d_out, int out_size, void* d_ws, size_t ws_size,
                              hipStream_t stream) {
    const float* x   = (const float*)d_in[0];
    const int*   adj = (const int*)d_in[1];
    const float* W   = (const float*)d_in[2];
    const float* a   = (const float*)d_in[3];
    float* out = (float*)d_out;

    char* ws = (char*)d_ws;
    short*         xF   = (short*)ws;                      // 4 MiB
    short*         WtF  = (short*)(ws + 4194304);          // 256 KiB
    unsigned char* VtF8 = (unsigned char*)(ws + 4456448);  // 1 MiB
    unsigned*      pT   = (unsigned*)(ws + 5505024);       // 2 MiB
    float*         ipk  = (float*)(ws + 7602176);          // 64 KiB
    float2*        jpk  = (float2*)(ws + 7667712);         // 128 KiB

    stage1  <<<1088, 256, 0, stream>>>(x, W, xF, WtF);
    stage2  <<<16640, 256, 0, stream>>>(xF, WtF, a, adj, VtF8, ipk, jpk, pT);
    gat_attn<<<512, 512, 0, stream>>>((const uint4*)pT, ipk, (const float*)jpk, VtF8, out);
}